// Round 1
// baseline (121.474 us; speedup 1.0000x reference)
//
#include <hip/hip_runtime.h>
#include <hip/hip_bf16.h>

#define Bsz 256
#define Tn 2048
#define QD 1024
#define AD 128
#define DCn 8
#define DKn 21
#define PLn 11
#define GN (DCn * DKn)   // 168
#define XS2 24           // X row stride in halfs (48 B; rows 16B-aligned)

#define ABLK 4           // batches per g_pre block
#define NGBLK (Bsz / ABLK)   // 64

typedef _Float16 f16x8 __attribute__((ext_vector_type(8)));
typedef float f32x4 __attribute__((ext_vector_type(4)));

#define TWO_LOG2E 2.8853900817779268f   // 2*log2(e): folds tanh's 2x and exp->exp2

// ---------------------------------------------------------------------------
// Kernel A: G precompute, 4 batches per block (64 blocks x 1024 threads).
//   h[b][a] = tanh(W_w[a] . q_b + W_b[a])   (wave handles 8 a-rows, q for the
//             4 b's held in registers -> W_w row loaded ONCE per 4 batches;
//             total W_w L2 traffic 128 MB -> 32 MB)
//   G[b][r] = V_w[r] . h[b]                 (672 threads, float4 loads)
// Output layout: G_all[b * Tn + r]  (row-strided so it can alias `out` safely:
// block b of the main kernel reads only row b before writing row b).
// ---------------------------------------------------------------------------
__global__ __launch_bounds__(1024, 4) void g_pre_kernel(
    const float* __restrict__ query, const float* __restrict__ W_w,
    const float* __restrict__ W_b, const float* __restrict__ V_w,
    float* __restrict__ G_all)
{
    __shared__ float h_lds[ABLK][AD];

    const int tid  = threadIdx.x;
    const int lane = tid & 63;
    const int wid  = tid >> 6;
    const int b0   = blockIdx.x * ABLK;

    // q fragments for 4 batches: 16 float4 per lane (same lane pattern as W rows)
    float4 q[ABLK][4];
    #pragma unroll
    for (int bb = 0; bb < ABLK; ++bb) {
        const float4* q4 = (const float4*)(query + (size_t)(b0 + bb) * QD);
        #pragma unroll
        for (int c = 0; c < 4; ++c) q[bb][c] = q4[c * 64 + lane];
    }

    // 8 a-rows per wave; W row loaded once, dotted with all 4 q's
    #pragma unroll 1
    for (int i = 0; i < 8; ++i) {
        const int a = wid * 8 + i;
        const float4* w4 = (const float4*)(W_w + (size_t)a * QD);
        float4 w0 = w4[lane];
        float4 w1 = w4[64 + lane];
        float4 w2 = w4[128 + lane];
        float4 w3 = w4[192 + lane];

        float acc[ABLK];
        #pragma unroll
        for (int bb = 0; bb < ABLK; ++bb) {
            float accA = 0.f, accB = 0.f;
            accA = fmaf(q[bb][0].x, w0.x, fmaf(q[bb][0].y, w0.y, fmaf(q[bb][0].z, w0.z, fmaf(q[bb][0].w, w0.w, accA))));
            accB = fmaf(q[bb][1].x, w1.x, fmaf(q[bb][1].y, w1.y, fmaf(q[bb][1].z, w1.z, fmaf(q[bb][1].w, w1.w, accB))));
            accA = fmaf(q[bb][2].x, w2.x, fmaf(q[bb][2].y, w2.y, fmaf(q[bb][2].z, w2.z, fmaf(q[bb][2].w, w2.w, accA))));
            accB = fmaf(q[bb][3].x, w3.x, fmaf(q[bb][3].y, w3.y, fmaf(q[bb][3].z, w3.z, fmaf(q[bb][3].w, w3.w, accB))));
            acc[bb] = accA + accB;
        }
        #pragma unroll
        for (int bb = 0; bb < ABLK; ++bb) {
            float v = acc[bb];
            #pragma unroll
            for (int off = 32; off; off >>= 1) v += __shfl_xor(v, off);
            acc[bb] = v;
        }
        if (lane == 0) {
            const float wb = W_b[a];
            #pragma unroll
            for (int bb = 0; bb < ABLK; ++bb) h_lds[bb][a] = tanhf(acc[bb] + wb);
        }
    }
    __syncthreads();

    // G = V_w h for 4 batches: one (b, row) per thread, float4 streams
    if (tid < ABLK * GN) {
        const int bb = tid / GN;
        const int r  = tid - bb * GN;
        const float4* v4 = (const float4*)(V_w + (size_t)r * AD);
        const float4* h4 = (const float4*)h_lds[bb];
        float g = 0.f;
        #pragma unroll 8
        for (int i = 0; i < AD / 4; ++i) {
            float4 vv = v4[i];
            float4 hh = h4[i];
            g = fmaf(vv.x, hh.x, fmaf(vv.y, hh.y, fmaf(vv.z, hh.z, fmaf(vv.w, hh.w, g))));
        }
        G_all[(size_t)(b0 + bb) * Tn + r] = g;
    }
}

// ---------------------------------------------------------------------------
// Kernel B: main fused conv-attention. Per b (one 1024-thread block):
//   [stage]    al16 staging + G_lds load (one coalesced 168-float read)
//   [prior]    pcb[t] = clip(conv(al, P)) wave-locally
//   [main]     per wave, 4 iters x 2 tiles of 16 t, zero block barriers:
//              conv-MFMA (im2col) -> wave-private LDS transpose ->
//              proj-MFMA SWAPPED: d = mfma(Wfrag, Xfrag) = y^T[a][t]
//              -> tanh via exp2/rcp with in-lane v-weights -> 2-shuffle reduce
//   [softmax]  s = pcb * exp(e_inner); block sum; normalize.
// Single block barrier before the main loop (was two: g-phases removed).
// ---------------------------------------------------------------------------
__global__ __launch_bounds__(1024, 4) void dca_kernel(
    const float* __restrict__ align, const float* __restrict__ P,
    const float* __restrict__ F_w, const float* __restrict__ U_w,
    const float* __restrict__ T_w, const float* __restrict__ T_b,
    const float* __restrict__ v_w, const float* __restrict__ G_all,
    float* __restrict__ out)
{
    __shared__ _Float16 al16[Tn + 44];
    __shared__ float    pcb[Tn];
    __shared__ float    sden[Tn];
    __shared__ _Float16 Xw[16 * 2 * 16 * XS2];  // 2 tiles/wave, 16 waves
    __shared__ float    G_lds[GN];
    __shared__ float    red[16];
    __shared__ float    bc;

    const int b    = blockIdx.x;
    const int tid  = threadIdx.x;
    const int lane = tid & 63;
    const int wid  = tid >> 6;
    const int l15  = lane & 15;
    const int quad = lane >> 4;

    // ---- stage alignment row as f16 (pad=10 each side; index i ~ t=i-10) ----
    for (int i = tid; i < Tn + 44; i += 1024) {
        int s = i - 10;
        float v = (s >= 0 && s < Tn) ? align[b * Tn + s] : 0.f;
        al16[i] = (_Float16)v;
    }

    // ---- G load (precomputed by g_pre_kernel; row-strided) ----
    if (tid < GN) G_lds[tid] = G_all[(size_t)b * Tn + tid];

    __syncthreads();   // al16 + G_lds ready

    // ---- prior, wave-local (same wave writes & reads its pcb range) ----
    const int t0w = wid * 128;
    #pragma unroll
    for (int tt = 0; tt < 2; ++tt) {
        int t = t0w + tt * 64 + lane;
        float pr = 0.f;
        #pragma unroll
        for (int k = 0; k < PLn; ++k) pr = fmaf((float)al16[t + k], P[k], pr);
        pcb[t] = fmaxf(pr, 1e-6f);
    }

    // ---- conv B-frag: B[k=quad*8+j][n=c=l15] = W'[c][k], taps>=21 zero ----
    f16x8 Bc = {};
    #pragma unroll
    for (int j = 0; j < 8; ++j) {
        int k = quad * 8 + j;
        float wv = 0.f;
        if (k < DKn) wv = (l15 < 8) ? F_w[l15 * DKn + k]
                                    : G_lds[(l15 - 8) * DKn + k];
        Bc[j] = (_Float16)wv;
    }

    // ---- proj weight frags (used as MFMA *A* operand: A[m=a_loc=l15][k]) ----
    // k=0..7: U (f-channels), k=8..15: T (g-channels), k=16: bias channel.
    f16x8 Bf[8];
    #pragma unroll
    for (int n = 0; n < 8; ++n) {
        int a = n * 16 + l15;
        f16x8 bf = {};
        if (quad < 2) {
            const float* src = (quad == 0) ? (U_w + a * 8) : (T_w + a * 8);
            float4 lo = ((const float4*)src)[0];
            float4 hi = ((const float4*)src)[1];
            bf[0] = (_Float16)(TWO_LOG2E * lo.x); bf[1] = (_Float16)(TWO_LOG2E * lo.y);
            bf[2] = (_Float16)(TWO_LOG2E * lo.z); bf[3] = (_Float16)(TWO_LOG2E * lo.w);
            bf[4] = (_Float16)(TWO_LOG2E * hi.x); bf[5] = (_Float16)(TWO_LOG2E * hi.y);
            bf[6] = (_Float16)(TWO_LOG2E * hi.z); bf[7] = (_Float16)(TWO_LOG2E * hi.w);
        } else if (quad == 2) {
            bf[0] = (_Float16)(TWO_LOG2E * T_b[a]);   // k=16 bias channel
        }
        Bf[n] = bf;
    }

    // ---- in-lane v-weights: vnq[n][r] = -2*v_w[n*16 + quad*4 + r] ----
    f32x4 vnq[8];
    float vsum = 0.f;
    #pragma unroll
    for (int n = 0; n < 8; ++n) {
        f32x4 vq = *(const f32x4*)(v_w + n * 16 + quad * 4);
        vsum += vq[0] + vq[1] + vq[2] + vq[3];
        vq[0] *= -2.f; vq[1] *= -2.f; vq[2] *= -2.f; vq[3] *= -2.f;
        vnq[n] = vq;
    }
    vsum += __shfl_xor(vsum, 16);
    vsum += __shfl_xor(vsum, 32);   // full sum over 128 a's

    // ---- wave-local main loop: 4 iterations of 2 tiles (32 t) ----
    _Float16* Xp0 = &Xw[wid * 2 * 16 * XS2];
    _Float16* Xp1 = Xp0 + 16 * XS2;
    float wsum = 0.f;

    #pragma unroll 1
    for (int m = 0; m < 8; m += 2) {
        const int ta  = t0w + m * 16;
        const int tb_ = ta + 16;

        // conv A-frags: A[m=t_loc=l15][k=tap=quad*8+j]
        f16x8 Ac0, Ac1;
        #pragma unroll
        for (int j = 0; j < 8; ++j) {
            Ac0[j] = al16[ta  + l15 + quad * 8 + j];
            Ac1[j] = al16[tb_ + l15 + quad * 8 + j];
        }
        f32x4 z = {};
        f32x4 X0 = __builtin_amdgcn_mfma_f32_16x16x32_f16(Ac0, Bc, z, 0, 0, 0);
        f32x4 X1 = __builtin_amdgcn_mfma_f32_16x16x32_f16(Ac1, Bc, z, 0, 0, 0);

        // D[m=t_loc=quad*4+r][n=c=l15] -> wave-private LDS tiles [t_loc][c]
        #pragma unroll
        for (int r = 0; r < 4; ++r) {
            Xp0[(quad * 4 + r) * XS2 + l15] = (_Float16)X0[r];
            Xp1[(quad * 4 + r) * XS2 + l15] = (_Float16)X1[r];
        }
        __asm__ __volatile__("" ::: "memory");  // keep order; HW DS is in-order/wave

        // X^T frags (MFMA *B* operand): B[k=c=quad*8+j][n=t_loc=l15];
        // k=16 (quad2,j0) = 1.0 feeds the bias channel.
        f16x8 B20 = {}, B21 = {};
        if (quad < 2) {
            B20 = *(const f16x8*)&Xp0[l15 * XS2 + quad * 8];
            B21 = *(const f16x8*)&Xp1[l15 * XS2 + quad * 8];
        } else if (quad == 2) {
            B20[0] = (_Float16)1.f;
            B21[0] = (_Float16)1.f;
        }

        float es0 = 0.f, es1 = 0.f;
        #pragma unroll
        for (int n = 0; n < 8; ++n) {
            f32x4 z2 = {};
            // swapped operands: D[m=a_loc][n=t]: row=a_loc=quad*4+r, col=t=l15
            f32x4 d0 = __builtin_amdgcn_mfma_f32_16x16x32_f16(Bf[n], B20, z2, 0, 0, 0);
            f32x4 d1 = __builtin_amdgcn_mfma_f32_16x16x32_f16(Bf[n], B21, z2, 0, 0, 0);
            #pragma unroll
            for (int r = 0; r < 4; ++r) {
                float qa = __builtin_amdgcn_exp2f(d0[r]);
                float qb = __builtin_amdgcn_exp2f(d1[r]);
                float ra = __builtin_amdgcn_rcpf(qa + 1.f);
                float rb = __builtin_amdgcn_rcpf(qb + 1.f);
                es0 = fmaf(vnq[n][r], ra, es0);
                es1 = fmaf(vnq[n][r], rb, es1);
            }
        }
        // full a-reduction: only across quads now (t = l15 is the lane col)
        es0 += __shfl_xor(es0, 16);
        es0 += __shfl_xor(es0, 32);
        es1 += __shfl_xor(es1, 16);
        es1 += __shfl_xor(es1, 32);

        if (lane < 16) {
            int tA = ta  + lane;
            int tB = tb_ + lane;
            float svA = pcb[tA] * __expf(es0 + vsum);
            float svB = pcb[tB] * __expf(es1 + vsum);
            sden[tA] = svA;
            sden[tB] = svB;
            wsum += svA + svB;
        }
    }

    // ---- block sum + normalize ----
    __syncthreads();
    #pragma unroll
    for (int off = 32; off; off >>= 1) wsum += __shfl_xor(wsum, off);
    if (lane == 0) red[wid] = wsum;
    __syncthreads();
    if (wid == 0) {
        float ss = (lane < 16) ? red[lane] : 0.f;
        #pragma unroll
        for (int off = 8; off; off >>= 1) ss += __shfl_xor(ss, off);
        if (lane == 0) bc = ss;
    }
    __syncthreads();
    const float inv = 1.f / bc;
    out[b * Tn + tid]        = sden[tid] * inv;
    out[b * Tn + tid + 1024] = sden[tid + 1024] * inv;
}

// ---------------------------------------------------------------------------
extern "C" void kernel_launch(void* const* d_in, const int* in_sizes, int n_in,
                              void* d_out, int out_size, void* d_ws, size_t ws_size,
                              hipStream_t stream) {
    const float* query = (const float*)d_in[0];
    const float* align = (const float*)d_in[1];
    const float* P     = (const float*)d_in[2];
    const float* W_w   = (const float*)d_in[3];
    const float* W_b   = (const float*)d_in[4];
    const float* V_w   = (const float*)d_in[5];
    const float* F_w   = (const float*)d_in[6];
    const float* U_w   = (const float*)d_in[7];
    const float* T_w   = (const float*)d_in[8];
    const float* T_b   = (const float*)d_in[9];
    const float* v_w   = (const float*)d_in[10];
    float* out = (float*)d_out;

    // G staging buffer: row-strided (b*Tn + r). Prefer workspace; fall back to
    // `out` (safe: main-kernel block b reads only row b's G before writing row b).
    float* Gbuf = (ws_size >= (size_t)Bsz * Tn * sizeof(float)) ? (float*)d_ws
                                                                : out;

    g_pre_kernel<<<NGBLK, 1024, 0, stream>>>(query, W_w, W_b, V_w, Gbuf);
    dca_kernel<<<Bsz, 1024, 0, stream>>>(align, P, F_w, U_w, T_w, T_b, v_w,
                                         Gbuf, out);
}

// Round 2
// 104.092 us; speedup vs baseline: 1.1670x; 1.1670x over previous
//
#include <hip/hip_runtime.h>
#include <hip/hip_bf16.h>

#define Bsz 256
#define Tn 2048
#define QD 1024
#define AD 128
#define DCn 8
#define DKn 21
#define PLn 11
#define GN (DCn * DKn)   // 168

typedef _Float16 f16x8 __attribute__((ext_vector_type(8)));
typedef float f32x4 __attribute__((ext_vector_type(4)));
typedef unsigned int u32;

#define TWO_LOG2E 2.8853900817779268f   // 2*log2(e): folds tanh's 2x and exp->exp2

// RNE pack of two floats into a (f16,f16) dword — matches (_Float16) cast rounding.
__device__ __forceinline__ u32 pkh_rne(float a, float b) {
    union { _Float16 h[2]; u32 u; } p;
    p.h[0] = (_Float16)a; p.h[1] = (_Float16)b;
    return p.u;
}

// ---------------------------------------------------------------------------
// Single fused kernel (revert of the two-kernel split: serialization cost it
// +14 µs). Per b (one 1024-thread block):
//   [stage]    al16 staged via float4 loads + packed b32 LDS writes
//   [g-phase]  h = tanh(W_w q + W_b) (overlaps staging), G = V_w h (float4)
//   [prior]    pcb[t] = clip(conv(al, P)) wave-locally
//   [main]     per wave, 4 iters x 2 tiles of 16 t, zero block barriers:
//              SWAPPED conv-MFMA: X^T = mfma(Wc, al_frag) -> D[c][t]
//              (row=c=quad*4+r, col=t=l15) -> proj B-frag built IN-REGISTER
//              via 2 packs + 4 ds_bpermute (replaces the LDS write->read
//              transpose round-trip of the previous version) ->
//              proj-MFMA swapped: d = mfma(Wproj, X^T) = y^T[a][t] ->
//              tanh via exp2/rcp, v-weighted quad reduce (2 shuffles).
//   [softmax]  s = pcb * exp(e_inner); block sum; normalize.
// ---------------------------------------------------------------------------
__global__ __launch_bounds__(1024, 4) void dca_kernel(
    const float* __restrict__ query, const float* __restrict__ align,
    const float* __restrict__ P, const float* __restrict__ W_w,
    const float* __restrict__ W_b, const float* __restrict__ V_w,
    const float* __restrict__ F_w, const float* __restrict__ U_w,
    const float* __restrict__ T_w, const float* __restrict__ T_b,
    const float* __restrict__ v_w, float* __restrict__ out)
{
    __shared__ __align__(16) _Float16 al16[Tn + 44];
    __shared__ float    pcb[Tn];
    __shared__ float    sden[Tn];
    __shared__ __align__(16) float h_lds[AD];
    __shared__ float    G_lds[GN];
    __shared__ float    red[16];
    __shared__ float    bc;

    const int b    = blockIdx.x;
    const int tid  = threadIdx.x;
    const int lane = tid & 63;
    const int wid  = tid >> 6;
    const int l15  = lane & 15;
    const int quad = lane >> 4;

    // ---- stage alignment row as f16 (pad=10 each side; index i ~ t=i-10) ----
    // Vectorized: 512 threads x float4 + 2 packed b32 LDS writes; 64 threads
    // zero the 44 pad elements.
    if (tid < 512) {
        float4 v = ((const float4*)(align + (size_t)b * Tn))[tid];
        u32* dst = (u32*)&al16[10 + tid * 4];   // byte off 20+8*tid: 4B aligned
        dst[0] = pkh_rne(v.x, v.y);
        dst[1] = pkh_rne(v.z, v.w);
    } else if (tid < 576) {
        int k = tid - 512;
        if (k < 10)       al16[k]      = (_Float16)0.f;   // left pad 0..9
        else if (k < 44)  al16[Tn + k] = (_Float16)0.f;   // right pad Tn+10..Tn+43
    }

    // ---- g-phase 1: h = tanh(W_w q + W_b); wave handles 8 a-rows ----
    {
        const float4* q4 = (const float4*)(query + (size_t)b * QD);
        float4 q0 = q4[lane];
        float4 q1 = q4[64 + lane];
        float4 q2 = q4[128 + lane];
        float4 q3 = q4[192 + lane];
        #pragma unroll 2
        for (int i = 0; i < 8; ++i) {
            int a = wid * 8 + i;
            const float4* w4 = (const float4*)(W_w + (size_t)a * QD);
            float4 x0 = w4[lane];
            float4 x1 = w4[64 + lane];
            float4 x2 = w4[128 + lane];
            float4 x3 = w4[192 + lane];
            float accA = 0.f, accB = 0.f;
            accA = fmaf(q0.x, x0.x, fmaf(q0.y, x0.y, fmaf(q0.z, x0.z, fmaf(q0.w, x0.w, accA))));
            accB = fmaf(q1.x, x1.x, fmaf(q1.y, x1.y, fmaf(q1.z, x1.z, fmaf(q1.w, x1.w, accB))));
            accA = fmaf(q2.x, x2.x, fmaf(q2.y, x2.y, fmaf(q2.z, x2.z, fmaf(q2.w, x2.w, accA))));
            accB = fmaf(q3.x, x3.x, fmaf(q3.y, x3.y, fmaf(q3.z, x3.z, fmaf(q3.w, x3.w, accB))));
            float acc = accA + accB;
            #pragma unroll
            for (int off = 32; off; off >>= 1) acc += __shfl_xor(acc, off);
            if (lane == 0) h_lds[a] = tanhf(acc + W_b[a]);
        }
    }
    __syncthreads();   // h_lds + al16 ready

    // ---- g-phase 2: G = V_w h (168 rows, one thread each, float4 streams) ----
    if (tid < GN) {
        const float4* v4 = (const float4*)(V_w + (size_t)tid * AD);
        const float4* h4 = (const float4*)h_lds;
        float g = 0.f;
        #pragma unroll 8
        for (int i = 0; i < AD / 4; ++i) {
            float4 vv = v4[i];
            float4 hh = h4[i];
            g = fmaf(vv.x, hh.x, fmaf(vv.y, hh.y, fmaf(vv.z, hh.z, fmaf(vv.w, hh.w, g))));
        }
        G_lds[tid] = g;
    }

    // ---- prior, wave-local (same wave writes & reads its pcb range) ----
    const int t0w = wid * 128;
    #pragma unroll
    for (int tt = 0; tt < 2; ++tt) {
        int t = t0w + tt * 64 + lane;
        float pr = 0.f;
        #pragma unroll
        for (int k = 0; k < PLn; ++k) pr = fmaf((float)al16[t + k], P[k], pr);
        pcb[t] = fmaxf(pr, 1e-6f);
    }
    __syncthreads();   // G_lds ready

    // ---- conv weight frag (MFMA *A* operand): A[m=c=l15][k=tap=quad*8+j] ----
    f16x8 Bc = {};
    #pragma unroll
    for (int j = 0; j < 8; ++j) {
        int k = quad * 8 + j;
        float wv = 0.f;
        if (k < DKn) wv = (l15 < 8) ? F_w[l15 * DKn + k]
                                    : G_lds[(l15 - 8) * DKn + k];
        Bc[j] = (_Float16)wv;
    }

    // ---- proj weight frags (MFMA *A* operand: A[m=a_loc=l15][k]) ----
    // k=0..7: U (f-channels), k=8..15: T (g-channels), k=16: bias channel.
    f16x8 Bf[8];
    #pragma unroll
    for (int n = 0; n < 8; ++n) {
        int a = n * 16 + l15;
        f16x8 bf = {};
        if (quad < 2) {
            const float* src = (quad == 0) ? (U_w + a * 8) : (T_w + a * 8);
            float4 lo = ((const float4*)src)[0];
            float4 hi = ((const float4*)src)[1];
            bf[0] = (_Float16)(TWO_LOG2E * lo.x); bf[1] = (_Float16)(TWO_LOG2E * lo.y);
            bf[2] = (_Float16)(TWO_LOG2E * lo.z); bf[3] = (_Float16)(TWO_LOG2E * lo.w);
            bf[4] = (_Float16)(TWO_LOG2E * hi.x); bf[5] = (_Float16)(TWO_LOG2E * hi.y);
            bf[6] = (_Float16)(TWO_LOG2E * hi.z); bf[7] = (_Float16)(TWO_LOG2E * hi.w);
        } else if (quad == 2) {
            bf[0] = (_Float16)(TWO_LOG2E * T_b[a]);   // k=16 bias channel
        }
        Bf[n] = bf;
    }

    // ---- in-lane v-weights: vnq[n][r] = -2*v_w[n*16 + quad*4 + r] ----
    f32x4 vnq[8];
    float vsum = 0.f;
    #pragma unroll
    for (int n = 0; n < 8; ++n) {
        f32x4 vq = *(const f32x4*)(v_w + n * 16 + quad * 4);
        vsum += vq[0] + vq[1] + vq[2] + vq[3];
        vq[0] *= -2.f; vq[1] *= -2.f; vq[2] *= -2.f; vq[3] *= -2.f;
        vnq[n] = vq;
    }
    vsum += __shfl_xor(vsum, 16);
    vsum += __shfl_xor(vsum, 32);   // full sum over 128 a's

    // bpermute source addresses: target (quad,l15) pulls from lanes
    // (2*quad)*16+l15 (srcA: c=quad*8+0..3) and +16 (srcB: c=quad*8+4..7).
    // quad>=2 wraps to garbage lanes — harmless (Bf zero there), except the
    // bias word k=16 which is overwritten below.
    const int addrA = ((((lane & 48) << 1) | (lane & 15)) << 2);
    const int addrB = addrA + 64;

    // ---- wave-local main loop: 4 iterations of 2 tiles (32 t) ----
    float wsum = 0.f;

    #pragma unroll 1
    for (int m = 0; m < 8; m += 2) {
        const int ta  = t0w + m * 16;
        const int tb_ = ta + 16;

        // conv al-frags (MFMA *B* operand): B[k=tap=quad*8+j][n=t_loc=l15]
        f16x8 Ac0, Ac1;
        #pragma unroll
        for (int j = 0; j < 8; ++j) {
            Ac0[j] = al16[ta  + l15 + quad * 8 + j];
            Ac1[j] = al16[tb_ + l15 + quad * 8 + j];
        }
        f32x4 z = {};
        // swapped conv: D[m=c][n=t]; lane holds c=quad*4+r, t=ta+l15
        f32x4 X0 = __builtin_amdgcn_mfma_f32_16x16x32_f16(Bc, Ac0, z, 0, 0, 0);
        f32x4 X1 = __builtin_amdgcn_mfma_f32_16x16x32_f16(Bc, Ac1, z, 0, 0, 0);

        // in-register transpose gather: proj B-frag B2[k=c=quad*8+j][n=t=l15]
        u32 lo0 = pkh_rne(X0[0], X0[1]), hi0 = pkh_rne(X0[2], X0[3]);
        u32 lo1 = pkh_rne(X1[0], X1[1]), hi1 = pkh_rne(X1[2], X1[3]);

        union { u32 w[4]; f16x8 v; } U0, U1;
        U0.w[0] = (u32)__builtin_amdgcn_ds_bpermute(addrA, (int)lo0);
        U0.w[1] = (u32)__builtin_amdgcn_ds_bpermute(addrA, (int)hi0);
        U0.w[2] = (u32)__builtin_amdgcn_ds_bpermute(addrB, (int)lo0);
        U0.w[3] = (u32)__builtin_amdgcn_ds_bpermute(addrB, (int)hi0);
        U1.w[0] = (u32)__builtin_amdgcn_ds_bpermute(addrA, (int)lo1);
        U1.w[1] = (u32)__builtin_amdgcn_ds_bpermute(addrA, (int)hi1);
        U1.w[2] = (u32)__builtin_amdgcn_ds_bpermute(addrB, (int)lo1);
        U1.w[3] = (u32)__builtin_amdgcn_ds_bpermute(addrB, (int)hi1);
        if (quad == 2) {                  // k=16 bias channel = 1.0 (k=17 -> 0)
            U0.w[0] = 0x3C00u;
            U1.w[0] = 0x3C00u;
        }

        float es0 = 0.f, es1 = 0.f;
        #pragma unroll
        for (int n = 0; n < 8; ++n) {
            f32x4 z2 = {};
            // swapped operands: D[m=a_loc][n=t]: row=a_loc=quad*4+r, col=t=l15
            f32x4 d0 = __builtin_amdgcn_mfma_f32_16x16x32_f16(Bf[n], U0.v, z2, 0, 0, 0);
            f32x4 d1 = __builtin_amdgcn_mfma_f32_16x16x32_f16(Bf[n], U1.v, z2, 0, 0, 0);
            #pragma unroll
            for (int r = 0; r < 4; ++r) {
                float qa = __builtin_amdgcn_exp2f(d0[r]);
                float qb = __builtin_amdgcn_exp2f(d1[r]);
                float ra = __builtin_amdgcn_rcpf(qa + 1.f);
                float rb = __builtin_amdgcn_rcpf(qb + 1.f);
                es0 = fmaf(vnq[n][r], ra, es0);
                es1 = fmaf(vnq[n][r], rb, es1);
            }
        }
        // full a-reduction: only across quads (t = l15 is the lane col)
        es0 += __shfl_xor(es0, 16);
        es0 += __shfl_xor(es0, 32);
        es1 += __shfl_xor(es1, 16);
        es1 += __shfl_xor(es1, 32);

        if (lane < 16) {
            int tA = ta  + lane;
            int tB = tb_ + lane;
            float svA = pcb[tA] * __expf(es0 + vsum);
            float svB = pcb[tB] * __expf(es1 + vsum);
            sden[tA] = svA;
            sden[tB] = svB;
            wsum += svA + svB;
        }
    }

    // ---- block sum + normalize ----
    __syncthreads();
    #pragma unroll
    for (int off = 32; off; off >>= 1) wsum += __shfl_xor(wsum, off);
    if (lane == 0) red[wid] = wsum;
    __syncthreads();
    if (wid == 0) {
        float ss = (lane < 16) ? red[lane] : 0.f;
        #pragma unroll
        for (int off = 8; off; off >>= 1) ss += __shfl_xor(ss, off);
        if (lane == 0) bc = ss;
    }
    __syncthreads();
    const float inv = 1.f / bc;
    out[b * Tn + tid]        = sden[tid] * inv;
    out[b * Tn + tid + 1024] = sden[tid + 1024] * inv;
}

// ---------------------------------------------------------------------------
extern "C" void kernel_launch(void* const* d_in, const int* in_sizes, int n_in,
                              void* d_out, int out_size, void* d_ws, size_t ws_size,
                              hipStream_t stream) {
    const float* query = (const float*)d_in[0];
    const float* align = (const float*)d_in[1];
    const float* P     = (const float*)d_in[2];
    const float* W_w   = (const float*)d_in[3];
    const float* W_b   = (const float*)d_in[4];
    const float* V_w   = (const float*)d_in[5];
    const float* F_w   = (const float*)d_in[6];
    const float* U_w   = (const float*)d_in[7];
    const float* T_w   = (const float*)d_in[8];
    const float* T_b   = (const float*)d_in[9];
    const float* v_w   = (const float*)d_in[10];
    float* out = (float*)d_out;

    dca_kernel<<<Bsz, 1024, 0, stream>>>(query, align, P, W_w, W_b, V_w,
                                         F_w, U_w, T_w, T_b, v_w, out);
}